// Round 9
// baseline (678.224 us; speedup 1.0000x reference)
//
#include <hip/hip_runtime.h>
#include <hip/hip_bf16.h>

// NewellGRUModel: B=512, S=1024, F=16, H=64.  bf16 in/out (proven r2..r18).
//
// r19: move the recurrence to the MATRIX pipe. r13-r18 post-mortems: the
// VALU dot2 path pays a per-use cross-file copy for AGPR-parked weights
// (~2x dot cost) and cannot avoid parking at 96+ live dwords. MFMA reads
// A/B from AGPRs natively -> the tax vanishes. Design: 2 batches/block as
// rows 0 and 8 of one 16x16 M-tile; per step D[16x192] = A(h,f16).B(W,f16)
// + C(x_proj) via 24 x mfma_f32_16x16x32_f16 (~115 cyc issue, replaces
// 2x192 dot2 + copies ~770 cyc). A and B frags use the SAME (group,slot)->k
// map, so the contraction is exact for any HW slot order; C/D layout is the
// verified col=lane&15,row=(lane>>4)*4+reg. Gates on lane-groups 0 (batch A,
// row0) and 2 (batch B, row8). h LDS round-trip stays in-wave (in-order DS,
// no step barriers). Producer wave: x-proj both batches (r13 bit-order) into
// xp[2][2][16][192] + biases; barrier per 16-step tile only.

typedef _Float16 f16x8 __attribute__((ext_vector_type(8)));
typedef float    f32x4 __attribute__((ext_vector_type(4)));
union FU { unsigned int u; float f; };

#define MFMA16(a, b, c) __builtin_amdgcn_mfma_f32_16x16x32_f16((a), (b), (c), 0, 0, 0)

template<bool BF16>
struct IO {
    static __device__ __forceinline__ float ld(const void* p, int i) {
        if constexpr (BF16) {
            unsigned short u = ((const unsigned short*)p)[i];
            FU c; c.u = (unsigned int)u << 16;
            return c.f;
        } else {
            return ((const float*)p)[i];
        }
    }
    static __device__ __forceinline__ void st(void* p, int i, float v) {
        if constexpr (BF16) ((__hip_bfloat16*)p)[i] = __float2bfloat16(v);
        else ((float*)p)[i] = v;
    }
    static __device__ __forceinline__ float4 ld4(const void* p, int i) {
        if constexpr (BF16) {
            const ushort4 u = ((const ushort4*)p)[i >> 2];
            FU a, b, c, d;
            a.u = (unsigned int)u.x << 16; b.u = (unsigned int)u.y << 16;
            c.u = (unsigned int)u.z << 16; d.u = (unsigned int)u.w << 16;
            return make_float4(a.f, b.f, c.f, d.f);
        } else {
            return ((const float4*)p)[i >> 2];
        }
    }
};

// mode: 0 = buffers are bf16, 1 = buffers are fp32.
__global__ void detect_dtype_kernel(const void* rkbuf, int* flag) {
    const float* f = (const float*)rkbuf;
    int ok = 0;
    for (int i = 0; i < 64; ++i) {
        float a = fabsf(f[i]);
        ok += (a > 1e-5f && a < 2.0f) ? 1 : 0;
    }
    *flag = (ok >= 48) ? 1 : 0;
}

template<bool BF16>
__global__ __launch_bounds__(128, 1)
void gru_mm_kernel(const void* __restrict__ inp, const void* __restrict__ gk,
                   const void* __restrict__ rk,  const void* __restrict__ gb,
                   const void* __restrict__ w1,  const void* __restrict__ b1v,
                   const void* __restrict__ gam, const void* __restrict__ bet,
                   const void* __restrict__ muv, const void* __restrict__ vav,
                   const void* __restrict__ w2,  const void* __restrict__ bb2,
                   const void* __restrict__ Tp,  const int* __restrict__ mode,
                   void* __restrict__ out)
{
    const int want = BF16 ? 0 : 1;
    if (*mode != want) return;   // uniform branch, whole block exits

    const int b0  = blockIdx.x * 2;   // batches b0, b0+1
    const int tid = threadIdx.x;      // 0..127
    const int w   = tid >> 6;         // wave 0 = consumer(MFMA), 1 = producer
    const int l   = tid & 63;
    const int c   = l & 15;           // tile column
    const int lg  = l >> 4;           // lane group 0..3

    // xp[buf][batch][step][gate*64+unit], biases folded (z,r full; xh = b_i_h)
    __shared__ __align__(16) float xp[2][2][16][192];   // 48 KB
    __shared__ __align__(16) float xs[2][16][16];       // raw x (producer)
    __shared__ __align__(16) _Float16 hbuf[2][64];      // h rows (A operand src)
    __shared__ __align__(16) float sred[2][64];
    __shared__ float dsh[2];

    using io = IO<BF16>;

    if (w == 1) {
        // ================= PRODUCER (both batches, r13 bit-order) ==========
        float kz[15], kr[15], kh[15];
#pragma unroll
        for (int ch = 0; ch < 15; ++ch) {
            kz[ch] = io::ld(gk, ch*192 + l);
            kr[ch] = io::ld(gk, ch*192 + 64 + l);
            kh[ch] = io::ld(gk, ch*192 + 128 + l);
        }
        const float bz  = io::ld(gb, l)      + io::ld(gb, 192 + l);
        const float br  = io::ld(gb, 64 + l) + io::ld(gb, 192 + 64 + l);
        const float bax = io::ld(gb, 128 + l);
        float dsum0 = 0.0f, dsum1 = 0.0f;

        const int bat = l >> 5;       // staging role
        const int q   = l & 31;

        auto stage = [&](int t) {     // 256 f32 per batch per tile
            float4 v0 = io::ld4(inp, (b0 + bat)*16384 + t*256 + q*8);
            float4 v1 = io::ld4(inp, (b0 + bat)*16384 + t*256 + q*8 + 4);
            *(float4*)&xs[bat][q >> 1][(q & 1) * 8]     = v0;
            *(float4*)&xs[bat][q >> 1][(q & 1) * 8 + 4] = v1;
        };
        auto produce = [&](int buf) {
#pragma unroll 1
            for (int ab = 0; ab < 2; ++ab) {
#pragma unroll 1
                for (int s2 = 0; s2 < 16; ++s2) {
                    const float4* xr = (const float4*)&xs[ab][s2][0];
                    const float4 x0 = xr[0], x1 = xr[1], x2 = xr[2], x3 = xr[3];
                    const float xc[16] = {x0.x,x0.y,x0.z,x0.w, x1.x,x1.y,x1.z,x1.w,
                                          x2.x,x2.y,x2.z,x2.w, x3.x,x3.y,x3.z,x3.w};
                    float az = bz, ar = br, ax = bax;
#pragma unroll
                    for (int ch = 0; ch < 15; ++ch) {
                        az = fmaf(xc[ch], kz[ch], az);
                        ar = fmaf(xc[ch], kr[ch], ar);
                        ax = fmaf(xc[ch], kh[ch], ax);
                    }
                    if (ab == 0) dsum0 += xc[15]; else dsum1 += xc[15];
                    xp[buf][ab][s2][l]       = az;
                    xp[buf][ab][s2][64 + l]  = ar;
                    xp[buf][ab][s2][128 + l] = ax;
                }
            }
        };

        stage(0); produce(0);
        __syncthreads();                 // B0
#pragma unroll 1
        for (int t = 0; t < 64; ++t) {
            if (t < 63) {
                stage(t + 1);
                produce((t + 1) & 1);
            } else if (l == 0) {
                dsh[0] = dsum0; dsh[1] = dsum1;
            }
            __syncthreads();
        }
        return;
    }

    // ================= CONSUMER (MFMA) =================
    // B fragments: W_rec[k=64][192] as f16. Tile (gate g, nb), k-chunk kc:
    // lane holds B[32kc + 8*lg + j][16nb + c], j=0..7. Same k-map as A below.
    f16x8 Bz[2][4], Br[2][4], Bh[2][4];
#pragma unroll
    for (int kc = 0; kc < 2; ++kc)
#pragma unroll
        for (int nb = 0; nb < 4; ++nb) {
            f16x8 vz, vr, vh;
#pragma unroll
            for (int j = 0; j < 8; ++j) {
                const int kk = 32*kc + 8*lg + j;
                vz[j] = (_Float16)io::ld(rk, kk*192 +        16*nb + c);
                vr[j] = (_Float16)io::ld(rk, kk*192 +  64 +  16*nb + c);
                vh[j] = (_Float16)io::ld(rk, kk*192 + 128 +  16*nb + c);
            }
            Bz[kc][nb] = vz; Br[kc][nb] = vr; Bh[kc][nb] = vh;
        }
    float bahC[4];
#pragma unroll
    for (int nb = 0; nb < 4; ++nb)
        bahC[nb] = io::ld(gb, 192 + 128 + 16*nb + c);   // b_r[h] per unit

    const int bsel = lg >> 1;            // 0: batch A side, 1: batch B side
    float hold[4] = {0.0f, 0.0f, 0.0f, 0.0f};

    // A-read address: row r = c; r==0 -> batch A h, r==8 -> batch B h.
    const _Float16* habase = &hbuf[(c == 8) ? 1 : 0][8*lg];

    f16x8 A0 = {}, A1 = {};              // h0 = 0
    __syncthreads();                     // B0: tile 0 ready

    // C for (t=0, s2=0)
    float czv[4], crv[4], axv[4];
#pragma unroll
    for (int nb = 0; nb < 4; ++nb) {
        czv[nb] = xp[0][bsel][0][       16*nb + c];
        crv[nb] = xp[0][bsel][0][ 64 +  16*nb + c];
        axv[nb] = xp[0][bsel][0][128 +  16*nb + c];
    }

#pragma unroll 1
    for (int t = 0; t < 64; ++t) {
        const float (*xpt)[16][192] = xp[t & 1];
#pragma unroll 1
        for (int s2 = 0; s2 < 16; ++s2) {
            // ---- 24 MFMA: D = x_proj + h.W (rows 0,8 meaningful) ----
            f32x4 aZ[4], aR[4], aH[4];
#pragma unroll
            for (int nb = 0; nb < 4; ++nb) {
                const f32x4 cz = {czv[nb], czv[nb], czv[nb], czv[nb]};
                const f32x4 cr = {crv[nb], crv[nb], crv[nb], crv[nb]};
                const f32x4 ch = {bahC[nb], bahC[nb], bahC[nb], bahC[nb]};
                aZ[nb] = MFMA16(A0, Bz[0][nb], cz);
                aR[nb] = MFMA16(A0, Br[0][nb], cr);
                aH[nb] = MFMA16(A0, Bh[0][nb], ch);
                aZ[nb] = MFMA16(A1, Bz[1][nb], aZ[nb]);
                aR[nb] = MFMA16(A1, Br[1][nb], aR[nb]);
                aH[nb] = MFMA16(A1, Bh[1][nb], aH[nb]);
            }

            // ---- prefetch next step's C (same tile only) ----
            float nz[4], nr[4], nx[4];
            if (s2 < 15) {
#pragma unroll
                for (int nb = 0; nb < 4; ++nb) {
                    nz[nb] = xpt[bsel][s2+1][       16*nb + c];
                    nr[nb] = xpt[bsel][s2+1][ 64 +  16*nb + c];
                    nx[nb] = xpt[bsel][s2+1][128 +  16*nb + c];
                }
            }

            // ---- gates: lane groups 0 (row0=batch A) and 2 (row8=batch B) --
            if (!(lg & 1)) {
#pragma unroll
                for (int nb = 0; nb < 4; ++nb) {
                    const float az = aZ[nb][0], ar = aR[nb][0], ah = aH[nb][0];
                    const float z   = __builtin_amdgcn_rcpf(1.0f + __expf(-az));
                    const float r   = __builtin_amdgcn_rcpf(1.0f + __expf(-ar));
                    const float pre = fmaf(r, ah, axv[nb]);
                    const float e2  = __expf(2.0f * pre);
                    const float th  = 1.0f - 2.0f * __builtin_amdgcn_rcpf(e2 + 1.0f);
                    hold[nb] = fmaf(z, hold[nb] - th, th);
                    hbuf[bsel][16*nb + c] = (_Float16)hold[nb];
                }
            }

            // ---- A for next step (in-order DS: sees the writes above) ----
            A0 = *(const f16x8*)(habase);
            A1 = *(const f16x8*)(habase + 32);

            if (s2 < 15) {
#pragma unroll
                for (int nb = 0; nb < 4; ++nb) { czv[nb]=nz[nb]; crv[nb]=nr[nb]; axv[nb]=nx[nb]; }
            }
        }
        __syncthreads();                 // tile t done / t+1 ready
        if (t < 63) {
#pragma unroll
            for (int nb = 0; nb < 4; ++nb) {
                czv[nb] = xp[(t+1)&1][bsel][0][       16*nb + c];
                crv[nb] = xp[(t+1)&1][bsel][0][ 64 +  16*nb + c];
                axv[nb] = xp[(t+1)&1][bsel][0][128 +  16*nb + c];
            }
        }
    }

    // ---- epilogue: delta effect + dense head, both batches ----
    const float T0 = io::ld(Tp, 0);
    if (!(lg & 1)) {
#pragma unroll
        for (int nb = 0; nb < 4; ++nb)
            sred[bsel][16*nb + c] = fmaf(T0 * (1.0f / 1024.0f), dsh[bsel], hold[nb]);
    }
    // same-wave DS, in-order: reads below see the writes
    const int j = l;   // 0..63
    float accA = io::ld(b1v, j), accB = accA;
#pragma unroll
    for (int k = 0; k < 64; ++k) {
        const float wv = io::ld(w1, k*64 + j);
        accA = fmaf(sred[0][k], wv, accA);
        accB = fmaf(sred[1][k], wv, accB);
    }
    const float inv = rsqrtf(io::ld(vav, j) + 0.001f);       // BN_EPS
    const float mu = io::ld(muv, j), ga = io::ld(gam, j), be = io::ld(bet, j);
    accA = fmaf((fmaxf(accA, 0.0f) - mu) * inv, ga, be);
    accB = fmaf((fmaxf(accB, 0.0f) - mu) * inv, ga, be);

    const float w2j = io::ld(w2, j);
    float vA = accA * w2j, vB = accB * w2j;
#pragma unroll
    for (int off = 32; off > 0; off >>= 1) {
        vA += __shfl_down(vA, off);
        vB += __shfl_down(vB, off);
    }
    if (j == 0) {
        const float b2v = io::ld(bb2, 0);
        io::st(out, b0,     vA + b2v);
        io::st(out, b0 + 1, vB + b2v);
    }
}

extern "C" void kernel_launch(void* const* d_in, const int* in_sizes, int n_in,
                              void* d_out, int out_size, void* d_ws, size_t ws_size,
                              hipStream_t stream)
{
    const void* inp = d_in[0];   // (512,1024,16)
    const void* gk  = d_in[1];   // (15,192)
    const void* rk  = d_in[2];   // (64,192)
    const void* gb  = d_in[3];   // (2,192)
    const void* w1  = d_in[4];   // (64,64)
    const void* b1v = d_in[5];   // (64,)
    const void* gam = d_in[6];
    const void* bet = d_in[7];
    const void* muv = d_in[8];
    const void* vav = d_in[9];
    const void* w2  = d_in[10];  // (64,1)
    const void* bb2 = d_in[11];  // (1,)
    const void* Tp  = d_in[12];  // (1,)

    int* flag = (int*)d_ws;
    detect_dtype_kernel<<<dim3(1), dim3(1), 0, stream>>>(rk, flag);
    gru_mm_kernel<true ><<<dim3(256), dim3(128), 0, stream>>>(
        inp, gk, rk, gb, w1, b1v, gam, bet, muv, vav, w2, bb2, Tp, flag, d_out);
    gru_mm_kernel<false><<<dim3(256), dim3(128), 0, stream>>>(
        inp, gk, rk, gb, w1, b1v, gam, bet, muv, vav, w2, bb2, Tp, flag, d_out);
}

// Round 10
// 518.550 us; speedup vs baseline: 1.3079x; 1.3079x over previous
//
#include <hip/hip_runtime.h>
#include <hip/hip_bf16.h>

// NewellGRUModel: B=512, S=1024, F=16, H=64.  bf16 in/out (proven r2..r19).
//
// r20: r19 proved the MFMA fragment maps (absmax passed) but T_step=1421 vs
// ~450 issued. The excess was step-structure: divergent gate branch, 12
// scattered C-prefetch chains, C-operand splats (12 live f32x4 quads +
// accvgpr traffic). Rebuild consumer step, keep producer + fragments:
//  1) zero-C MFMA (one shared zero quad); x_proj added on the scalar path
//     after: az = aZ[nb][0] + czv[nb]. No splats.
//  2) uniform all-lane gates on reg0 (row 4*lg). Rows 0/8 real, rows 4/12
//     a closed garbage loop (D row r depends only on A row r; hbuf[16][64]
//     zero-init -> unwritten rows stay 0). No branch, no masked writes.
//  3) one-base addressing: czv/crv/cxv = 12 ds_read_b32 off a single base
//     (imm offsets), issued at step-top -> latency hides under the MFMAs;
//     h-writes 4 ds_write_b16 off a loop-invariant base; A 2 b128 off one
//     base. Same-wave in-order DS; one barrier per 16-step tile.

typedef _Float16 f16x8 __attribute__((ext_vector_type(8)));
typedef float    f32x4 __attribute__((ext_vector_type(4)));
union FU { unsigned int u; float f; };

#define MFMA16(a, b, c) __builtin_amdgcn_mfma_f32_16x16x32_f16((a), (b), (c), 0, 0, 0)

template<bool BF16>
struct IO {
    static __device__ __forceinline__ float ld(const void* p, int i) {
        if constexpr (BF16) {
            unsigned short u = ((const unsigned short*)p)[i];
            FU c; c.u = (unsigned int)u << 16;
            return c.f;
        } else {
            return ((const float*)p)[i];
        }
    }
    static __device__ __forceinline__ void st(void* p, int i, float v) {
        if constexpr (BF16) ((__hip_bfloat16*)p)[i] = __float2bfloat16(v);
        else ((float*)p)[i] = v;
    }
    static __device__ __forceinline__ float4 ld4(const void* p, int i) {
        if constexpr (BF16) {
            const ushort4 u = ((const ushort4*)p)[i >> 2];
            FU a, b, c, d;
            a.u = (unsigned int)u.x << 16; b.u = (unsigned int)u.y << 16;
            c.u = (unsigned int)u.z << 16; d.u = (unsigned int)u.w << 16;
            return make_float4(a.f, b.f, c.f, d.f);
        } else {
            return ((const float4*)p)[i >> 2];
        }
    }
};

// mode: 0 = buffers are bf16, 1 = buffers are fp32.
__global__ void detect_dtype_kernel(const void* rkbuf, int* flag) {
    const float* f = (const float*)rkbuf;
    int ok = 0;
    for (int i = 0; i < 64; ++i) {
        float a = fabsf(f[i]);
        ok += (a > 1e-5f && a < 2.0f) ? 1 : 0;
    }
    *flag = (ok >= 48) ? 1 : 0;
}

template<bool BF16>
__global__ __launch_bounds__(128, 1)
void gru_mm2_kernel(const void* __restrict__ inp, const void* __restrict__ gk,
                    const void* __restrict__ rk,  const void* __restrict__ gb,
                    const void* __restrict__ w1,  const void* __restrict__ b1v,
                    const void* __restrict__ gam, const void* __restrict__ bet,
                    const void* __restrict__ muv, const void* __restrict__ vav,
                    const void* __restrict__ w2,  const void* __restrict__ bb2,
                    const void* __restrict__ Tp,  const int* __restrict__ mode,
                    void* __restrict__ out)
{
    const int want = BF16 ? 0 : 1;
    if (*mode != want) return;   // uniform branch, whole block exits

    const int b0  = blockIdx.x * 2;   // batches b0, b0+1
    const int tid = threadIdx.x;      // 0..127
    const int w   = tid >> 6;         // wave 0 = consumer(MFMA), 1 = producer
    const int l   = tid & 63;
    const int c   = l & 15;           // tile column
    const int lg  = l >> 4;           // lane group 0..3

    // xp[buf][batch][step][gate*64+unit], biases folded (z,r full; xh = b_i_h)
    __shared__ __align__(16) float xp[2][2][16][192];   // 48 KB
    __shared__ __align__(16) float xs[2][16][16];       // raw x (producer)
    __shared__ __align__(16) _Float16 hbuf[16][64];     // h rows (A source)
    __shared__ __align__(16) float sred[2][64];
    __shared__ float dsh[2];

    using io = IO<BF16>;

    if (w == 1) {
        // ================= PRODUCER (both batches, r13 bit-order) ==========
        float kz[15], kr[15], kh[15];
#pragma unroll
        for (int ch = 0; ch < 15; ++ch) {
            kz[ch] = io::ld(gk, ch*192 + l);
            kr[ch] = io::ld(gk, ch*192 + 64 + l);
            kh[ch] = io::ld(gk, ch*192 + 128 + l);
        }
        const float bz  = io::ld(gb, l)      + io::ld(gb, 192 + l);
        const float br  = io::ld(gb, 64 + l) + io::ld(gb, 192 + 64 + l);
        const float bax = io::ld(gb, 128 + l);
        float dsum0 = 0.0f, dsum1 = 0.0f;

        const int bat = l >> 5;       // staging role
        const int q   = l & 31;

        auto stage = [&](int t) {     // 256 f32 per batch per tile
            float4 v0 = io::ld4(inp, (b0 + bat)*16384 + t*256 + q*8);
            float4 v1 = io::ld4(inp, (b0 + bat)*16384 + t*256 + q*8 + 4);
            *(float4*)&xs[bat][q >> 1][(q & 1) * 8]     = v0;
            *(float4*)&xs[bat][q >> 1][(q & 1) * 8 + 4] = v1;
        };
        auto produce = [&](int buf) {
#pragma unroll 1
            for (int ab = 0; ab < 2; ++ab) {
#pragma unroll 1
                for (int s2 = 0; s2 < 16; ++s2) {
                    const float4* xr = (const float4*)&xs[ab][s2][0];
                    const float4 x0 = xr[0], x1 = xr[1], x2 = xr[2], x3 = xr[3];
                    const float xc[16] = {x0.x,x0.y,x0.z,x0.w, x1.x,x1.y,x1.z,x1.w,
                                          x2.x,x2.y,x2.z,x2.w, x3.x,x3.y,x3.z,x3.w};
                    float az = bz, ar = br, ax = bax;
#pragma unroll
                    for (int ch = 0; ch < 15; ++ch) {
                        az = fmaf(xc[ch], kz[ch], az);
                        ar = fmaf(xc[ch], kr[ch], ar);
                        ax = fmaf(xc[ch], kh[ch], ax);
                    }
                    if (ab == 0) dsum0 += xc[15]; else dsum1 += xc[15];
                    xp[buf][ab][s2][l]       = az;
                    xp[buf][ab][s2][64 + l]  = ar;
                    xp[buf][ab][s2][128 + l] = ax;
                }
            }
        };

        stage(0); produce(0);
        __syncthreads();                 // B0
#pragma unroll 1
        for (int t = 0; t < 64; ++t) {
            if (t < 63) {
                stage(t + 1);
                produce((t + 1) & 1);
            } else if (l == 0) {
                dsh[0] = dsum0; dsh[1] = dsum1;
            }
            __syncthreads();
        }
        return;
    }

    // ================= CONSUMER (MFMA) =================
    // B fragments (r19-proven map): B[32kc + 8lg + j][16nb + c].
    f16x8 Bz[2][4], Br[2][4], Bh[2][4];
#pragma unroll
    for (int kc = 0; kc < 2; ++kc)
#pragma unroll
        for (int nb = 0; nb < 4; ++nb) {
            f16x8 vz, vr, vh;
#pragma unroll
            for (int j = 0; j < 8; ++j) {
                const int kk = 32*kc + 8*lg + j;
                vz[j] = (_Float16)io::ld(rk, kk*192 +        16*nb + c);
                vr[j] = (_Float16)io::ld(rk, kk*192 +  64 +  16*nb + c);
                vh[j] = (_Float16)io::ld(rk, kk*192 + 128 +  16*nb + c);
            }
            Bz[kc][nb] = vz; Br[kc][nb] = vr; Bh[kc][nb] = vh;
        }
    float bahC[4];
#pragma unroll
    for (int nb = 0; nb < 4; ++nb)
        bahC[nb] = io::ld(gb, 192 + 128 + 16*nb + c);   // b_r[h] per unit

    // zero-init h rows (rows never written later stay 0)
    {
        uint4* hz = (uint4*)hbuf;        // 2 KB = 128 uint4
        hz[l] = make_uint4(0,0,0,0);
        hz[64 + l] = make_uint4(0,0,0,0);
    }

    const int bsel = lg >> 1;            // xp side (garbage rows read A side)
    float hold[4] = {0.0f, 0.0f, 0.0f, 0.0f};

    // loop-invariant bases
    _Float16* wbase = &hbuf[4*lg][c];                 // writes: +16*nb halves
    const f16x8* rabase = (const f16x8*)&hbuf[c][8*lg]; // A0 at +0, A1 at +64B

    f16x8 A0 = {}, A1 = {};              // h0 = 0
    __syncthreads();                     // B0: tile 0 ready

#pragma unroll 1
    for (int t = 0; t < 64; ++t) {
        const float (*xpt)[16][192] = xp[t & 1];
#pragma unroll 1
        for (int s2 = 0; s2 < 16; ++s2) {
            // ---- C reads for THIS step: 12 b32 off one base, issued early;
            //      consumed only at gate time (~200 cyc later) ----
            const float* cb = &xpt[bsel][s2][c];
            float czv[4], crv[4], cxv[4];
#pragma unroll
            for (int nb = 0; nb < 4; ++nb) {
                czv[nb] = cb[16*nb];
                crv[nb] = cb[64 + 16*nb];
                cxv[nb] = cb[128 + 16*nb];
            }

            // ---- 24 MFMA, zero-C chains ----
            const f32x4 zq = {0.0f, 0.0f, 0.0f, 0.0f};
            f32x4 aZ[4], aR[4], aH[4];
#pragma unroll
            for (int nb = 0; nb < 4; ++nb) {
                aZ[nb] = MFMA16(A1, Bz[1][nb], MFMA16(A0, Bz[0][nb], zq));
                aR[nb] = MFMA16(A1, Br[1][nb], MFMA16(A0, Br[0][nb], zq));
                aH[nb] = MFMA16(A1, Bh[1][nb], MFMA16(A0, Bh[0][nb], zq));
            }

            // ---- uniform all-lane gates on reg0 (row 4*lg) ----
#pragma unroll
            for (int nb = 0; nb < 4; ++nb) {
                const float az = aZ[nb][0] + czv[nb];
                const float ar = aR[nb][0] + crv[nb];
                const float ah = aH[nb][0] + bahC[nb];
                const float z   = __builtin_amdgcn_rcpf(1.0f + __expf(-az));
                const float r   = __builtin_amdgcn_rcpf(1.0f + __expf(-ar));
                const float pre = fmaf(r, ah, cxv[nb]);
                const float e2  = __expf(2.0f * pre);
                const float th  = 1.0f - 2.0f * __builtin_amdgcn_rcpf(e2 + 1.0f);
                hold[nb] = fmaf(z, hold[nb] - th, th);
                wbase[16*nb] = (_Float16)hold[nb];   // ds_write_b16, imm offset
            }

            // ---- A for next step (in-order DS sees the writes above) ----
            A0 = rabase[0];
            A1 = rabase[4];              // +64 B = 32 halves
        }
        __syncthreads();                 // tile t done / t+1 ready
    }

    // ---- epilogue: delta effect + dense head, both batches ----
    const float T0 = io::ld(Tp, 0);
    if (lg == 0) {
#pragma unroll
        for (int nb = 0; nb < 4; ++nb)
            sred[0][16*nb + c] = fmaf(T0 * (1.0f / 1024.0f), dsh[0], hold[nb]);
    } else if (lg == 2) {
#pragma unroll
        for (int nb = 0; nb < 4; ++nb)
            sred[1][16*nb + c] = fmaf(T0 * (1.0f / 1024.0f), dsh[1], hold[nb]);
    }
    // same-wave DS, in-order: reads below see the writes
    const int j = l;   // 0..63
    float accA = io::ld(b1v, j), accB = accA;
#pragma unroll
    for (int k = 0; k < 64; ++k) {
        const float wv = io::ld(w1, k*64 + j);
        accA = fmaf(sred[0][k], wv, accA);
        accB = fmaf(sred[1][k], wv, accB);
    }
    const float inv = rsqrtf(io::ld(vav, j) + 0.001f);       // BN_EPS
    const float mu = io::ld(muv, j), ga = io::ld(gam, j), be = io::ld(bet, j);
    accA = fmaf((fmaxf(accA, 0.0f) - mu) * inv, ga, be);
    accB = fmaf((fmaxf(accB, 0.0f) - mu) * inv, ga, be);

    const float w2j = io::ld(w2, j);
    float vA = accA * w2j, vB = accB * w2j;
#pragma unroll
    for (int off = 32; off > 0; off >>= 1) {
        vA += __shfl_down(vA, off);
        vB += __shfl_down(vB, off);
    }
    if (j == 0) {
        const float b2v = io::ld(bb2, 0);
        io::st(out, b0,     vA + b2v);
        io::st(out, b0 + 1, vB + b2v);
    }
}

extern "C" void kernel_launch(void* const* d_in, const int* in_sizes, int n_in,
                              void* d_out, int out_size, void* d_ws, size_t ws_size,
                              hipStream_t stream)
{
    const void* inp = d_in[0];   // (512,1024,16)
    const void* gk  = d_in[1];   // (15,192)
    const void* rk  = d_in[2];   // (64,192)
    const void* gb  = d_in[3];   // (2,192)
    const void* w1  = d_in[4];   // (64,64)
    const void* b1v = d_in[5];   // (64,)
    const void* gam = d_in[6];
    const void* bet = d_in[7];
    const void* muv = d_in[8];
    const void* vav = d_in[9];
    const void* w2  = d_in[10];  // (64,1)
    const void* bb2 = d_in[11];  // (1,)
    const void* Tp  = d_in[12];  // (1,)

    int* flag = (int*)d_ws;
    detect_dtype_kernel<<<dim3(1), dim3(1), 0, stream>>>(rk, flag);
    gru_mm2_kernel<true ><<<dim3(256), dim3(128), 0, stream>>>(
        inp, gk, rk, gb, w1, b1v, gam, bet, muv, vav, w2, bb2, Tp, flag, d_out);
    gru_mm2_kernel<false><<<dim3(256), dim3(128), 0, stream>>>(
        inp, gk, rk, gb, w1, b1v, gam, bet, muv, vav, w2, bb2, Tp, flag, d_out);
}